// Round 1
// baseline (333.063 us; speedup 1.0000x reference)
//
#include <hip/hip_runtime.h>

// Fused CircularBoundaryBlock:
//   out = relu(LN(x + W2 @ relu(W1 @ [roll(x,1), x, roll(x,-1)] + b1) + b2))
// B=4, N=65536, H=128, fp32 I/O, bf16 MFMA internally.
//
// Tile = 64 rows. 4 waves/block, column-split: wave w owns cols [32w,32w+32).
// v2 change (occupancy lever): W1/W2 B-fragments are NO LONGER persistent in
// registers (that cost ~128 regs -> AGPR overflow -> 2 blocks/CU). A prep
// kernel packs them fragment-ordered as bf16 into d_ws; the GEMM loops are
// interchanged (ks outer) and stream frags from L2 with 1-step prefetch.
// True reg footprint ~100 -> __launch_bounds__(256,4) -> 4 blocks/CU.

typedef __bf16 bf16x8 __attribute__((ext_vector_type(8)));
typedef __bf16 bf16x4 __attribute__((ext_vector_type(4)));
typedef float  f32x4  __attribute__((ext_vector_type(4)));

#define H      128
#define NB     65536        // rows per batch
#define TILE   64
#define XS     136          // x LDS stride (bf16 elems): 68 words ≡ 4 mod 32
#define HSS    136          // h LDS stride (bf16 elems), keeps 16B-aligned rows
#define VS     132          // v LDS stride (f32 elems)
#define NTILES 4096         // 4 * 65536 / 64

#define W1P_ELEMS 49152     // 12 ks * 4 wid * 2 ct * 64 lane * 8
#define W2P_ELEMS 16384     // 4 ks * ...

// ---- prep: pack W1/W2 into per-wave MFMA B-fragment order (bf16) ----
// idx = ks*4096 + wid*1024 + ct*512 + lane*8 + j
// frag element j for lane (g,l) = W[(ks*32 + g*8 + j)*H + (wid*32 + ct*16 + l)]
__global__ __launch_bounds__(256)
void pack_w(const float* __restrict__ W1, const float* __restrict__ W2,
            __bf16* __restrict__ wp) {
    const int i = blockIdx.x * 256 + threadIdx.x;
    if (i >= W1P_ELEMS + W2P_ELEMS) return;
    const int isW2 = (i >= W1P_ELEMS);
    const int ib = isW2 ? i - W1P_ELEMS : i;
    const float* src = isW2 ? W2 : W1;
    const int j    = ib & 7;
    const int lane = (ib >> 3) & 63;
    const int ct   = (ib >> 9) & 1;
    const int w    = (ib >> 10) & 3;
    const int ks   = ib >> 12;
    const int row  = ks * 32 + (lane >> 4) * 8 + j;
    const int col  = w * 32 + ct * 16 + (lane & 15);
    wp[i] = (__bf16)src[row * H + col];
}

__global__ __launch_bounds__(256, 4)
void cbb_kernel(const float* __restrict__ x,
                const float* __restrict__ b1,
                const float* __restrict__ b2, const float* __restrict__ gamma,
                const float* __restrict__ beta,
                const __bf16* __restrict__ wp, float* __restrict__ out) {
    // region A: xs (66*136 bf16) + hs (64*136 bf16) = 35360 B
    // region B (aliased): vs (64*132 f32) = 33792 B
    __shared__ __align__(16) char raw[(66 * XS + 64 * HSS) * 2];
    __bf16* xs = (__bf16*)raw;
    __bf16* hs = xs + 66 * XS;
    float*  vs = (float*)raw;
    __shared__ float s_mu[64], s_rs[64], s_gamma[128], s_beta[128];

    const int tid  = threadIdx.x;
    const int wid  = tid >> 6;
    const int lane = tid & 63;
    const int l    = lane & 15;   // MFMA m / n index
    const int g    = lane >> 4;   // MFMA quad (k-chunk select)
    const int col0 = wid * 32;
    const int c0   = col0 + l;
    const int c1   = col0 + 16 + l;

    if (tid < 128) { s_gamma[tid] = gamma[tid]; s_beta[tid] = beta[tid]; }

    const float b1r0 = b1[c0], b1r1 = b1[c1];
    const float b2r0 = b2[c0], b2r1 = b2[c1];

    // per-thread bases into the packed weight buffer
    const __bf16* w1p = wp + (wid * 1024 + lane * 8);
    const __bf16* w2p = wp + W1P_ELEMS + (wid * 1024 + lane * 8);

    for (int t = blockIdx.x; t < NTILES; t += gridDim.x) {
        const int b  = t >> 10;
        const int n0 = (t & 1023) << 6;
        const size_t rowbase = (size_t)b * NB;

        __syncthreads();  // protect vs (aliases xs) from previous iteration readers

        // ---- stage x rows n0-1 .. n0+64 (circular within batch) as bf16 ----
        for (int q = tid; q < 66 * 32; q += 256) {
            const int r = q >> 5, c = q & 31;
            const int grow = (n0 - 1 + r + NB) & (NB - 1);
            const float4 f = *(const float4*)(x + ((rowbase + grow) * H + c * 4));
            bf16x4 v4;
            v4[0] = (__bf16)f.x; v4[1] = (__bf16)f.y;
            v4[2] = (__bf16)f.z; v4[3] = (__bf16)f.w;
            *(bf16x4*)(xs + r * XS + c * 4) = v4;
        }
        __syncthreads();

        // ---- GEMM1: h = relu(cat @ W1 + b1), cat via row offsets 0/1/2 ----
        // ks outer; weight frags streamed from L2 with 1-step prefetch.
        f32x4 acc[4][2];
#pragma unroll
        for (int rt = 0; rt < 4; ++rt)
#pragma unroll
            for (int ct = 0; ct < 2; ++ct)
                acc[rt][ct] = (f32x4){0.f, 0.f, 0.f, 0.f};

        bf16x8 wc0 = *(const bf16x8*)(w1p);
        bf16x8 wc1 = *(const bf16x8*)(w1p + 512);
#pragma unroll
        for (int ks = 0; ks < 12; ++ks) {
            const int ksn = (ks < 11) ? ks + 1 : 0;   // clamp: last prefetch is dead
            bf16x8 wn0 = *(const bf16x8*)(w1p + ksn * 4096);
            bf16x8 wn1 = *(const bf16x8*)(w1p + ksn * 4096 + 512);
            const int k = ks * 32 + g * 8;            // k in [0,384)
#pragma unroll
            for (int rt = 0; rt < 4; ++rt) {
                const int rb = rt * 16 + l;
                const bf16x8 a = *(const bf16x8*)(xs + (rb + (k >> 7)) * XS + (k & 127));
                acc[rt][0] = __builtin_amdgcn_mfma_f32_16x16x32_bf16(a, wc0, acc[rt][0], 0, 0, 0);
                acc[rt][1] = __builtin_amdgcn_mfma_f32_16x16x32_bf16(a, wc1, acc[rt][1], 0, 0, 0);
            }
            wc0 = wn0; wc1 = wn1;
        }

        // relu + bias -> hs (bf16, row-major), C-layout scatter
#pragma unroll
        for (int rt = 0; rt < 4; ++rt) {
#pragma unroll
            for (int i = 0; i < 4; ++i) {
                const int row = rt * 16 + g * 4 + i;
                hs[row * HSS + c0] = (__bf16)fmaxf(acc[rt][0][i] + b1r0, 0.f);
                hs[row * HSS + c1] = (__bf16)fmaxf(acc[rt][1][i] + b1r1, 0.f);
            }
        }
        __syncthreads();

        // ---- GEMM2: delta = h @ W2 (streamed weight frags) ----
        f32x4 acc2[4][2];
#pragma unroll
        for (int rt = 0; rt < 4; ++rt)
#pragma unroll
            for (int ct = 0; ct < 2; ++ct)
                acc2[rt][ct] = (f32x4){0.f, 0.f, 0.f, 0.f};

        bf16x8 vc0 = *(const bf16x8*)(w2p);
        bf16x8 vc1 = *(const bf16x8*)(w2p + 512);
#pragma unroll
        for (int ks = 0; ks < 4; ++ks) {
            const int ksn = (ks < 3) ? ks + 1 : 0;
            bf16x8 vn0 = *(const bf16x8*)(w2p + ksn * 4096);
            bf16x8 vn1 = *(const bf16x8*)(w2p + ksn * 4096 + 512);
#pragma unroll
            for (int rt = 0; rt < 4; ++rt) {
                const bf16x8 a = *(const bf16x8*)(hs + (rt * 16 + l) * HSS + ks * 32 + g * 8);
                acc2[rt][0] = __builtin_amdgcn_mfma_f32_16x16x32_bf16(a, vc0, acc2[rt][0], 0, 0, 0);
                acc2[rt][1] = __builtin_amdgcn_mfma_f32_16x16x32_bf16(a, vc1, acc2[rt][1], 0, 0, 0);
            }
            vc0 = vn0; vc1 = vn1;
        }

        // ---- residual: v = x + delta + b2 (x from bf16 LDS tile, row+1) ----
#pragma unroll
        for (int rt = 0; rt < 4; ++rt) {
#pragma unroll
            for (int i = 0; i < 4; ++i) {
                const int row = rt * 16 + g * 4 + i;
                acc2[rt][0][i] += b2r0 + (float)xs[(row + 1) * XS + c0];
                acc2[rt][1][i] += b2r1 + (float)xs[(row + 1) * XS + c1];
            }
        }
        __syncthreads();  // all xs/hs reads done; vs may now clobber them

#pragma unroll
        for (int rt = 0; rt < 4; ++rt) {
#pragma unroll
            for (int i = 0; i < 4; ++i) {
                const int row = rt * 16 + g * 4 + i;
                vs[row * VS + c0] = acc2[rt][0][i];
                vs[row * VS + c1] = acc2[rt][1][i];
            }
        }
        __syncthreads();

        // ---- LN stats: 4 threads per row ----
        {
            const int row = tid >> 2;
            const int cb  = (tid & 3) * 32;
            float s = 0.f, qq = 0.f;
#pragma unroll
            for (int c8 = 0; c8 < 8; ++c8) {
                const f32x4 vv = *(const f32x4*)(vs + row * VS + cb + c8 * 4);
#pragma unroll
                for (int e = 0; e < 4; ++e) { s += vv[e]; qq += vv[e] * vv[e]; }
            }
            s  += __shfl_xor(s, 1, 4);  s  += __shfl_xor(s, 2, 4);
            qq += __shfl_xor(qq, 1, 4); qq += __shfl_xor(qq, 2, 4);
            const float muv = s * (1.f / 128.f);
            const float var = qq * (1.f / 128.f) - muv * muv;
            if ((tid & 3) == 0) { s_mu[row] = muv; s_rs[row] = rsqrtf(var + 1e-5f); }
        }
        __syncthreads();

        // ---- normalize + relu + coalesced float4 store ----
        {
            const int row = tid >> 2;
            const int cb  = (tid & 3) * 32;
            const float muv = s_mu[row], rv = s_rs[row];
            float* op = out + (rowbase + n0 + row) * H + cb;
#pragma unroll
            for (int c8 = 0; c8 < 8; ++c8) {
                const f32x4 vv = *(const f32x4*)(vs + row * VS + cb + c8 * 4);
                const f32x4 gm = *(const f32x4*)(s_gamma + cb + c8 * 4);
                const f32x4 bt = *(const f32x4*)(s_beta + cb + c8 * 4);
                f32x4 o;
#pragma unroll
                for (int e = 0; e < 4; ++e)
                    o[e] = fmaxf((vv[e] - muv) * rv * gm[e] + bt[e], 0.f);
                *(f32x4*)(op + c8 * 4) = o;
            }
        }
    }
}

extern "C" void kernel_launch(void* const* d_in, const int* in_sizes, int n_in,
                              void* d_out, int out_size, void* d_ws, size_t ws_size,
                              hipStream_t stream) {
    const float* x     = (const float*)d_in[0];
    const float* W1    = (const float*)d_in[1];
    const float* b1    = (const float*)d_in[2];
    const float* W2    = (const float*)d_in[3];
    const float* b2    = (const float*)d_in[4];
    const float* gamma = (const float*)d_in[5];
    const float* beta  = (const float*)d_in[6];
    float* out = (float*)d_out;
    __bf16* wp = (__bf16*)d_ws;   // 131072 B packed weights

    // pack weights fragment-ordered (re-done every launch: inputs may be re-poisoned)
    pack_w<<<256, 256, 0, stream>>>(W1, W2, wp);

    // 1024 blocks = 4 resident blocks/CU * 256 CUs; grid-stride over 4096 tiles
    cbb_kernel<<<1024, 256, 0, stream>>>(x, b1, b2, gamma, beta, wp, out);
}

// Round 2
// 270.256 us; speedup vs baseline: 1.2324x; 1.2324x over previous
//
#include <hip/hip_runtime.h>

// Fused CircularBoundaryBlock:
//   out = relu(LN(x + W2 @ relu(W1 @ [roll(x,1), x, roll(x,-1)] + b1) + b2))
// B=4, N=65536, H=128, fp32 I/O, bf16 MFMA internally.
//
// Tile = 64 rows. 4 waves/block, column-split: wave w owns cols [32w,32w+32).
// v3: revert v2's weight streaming (it tripled HBM traffic and spilled).
//   - W1 B-fragments persistent in registers (96 regs, as v1).
//   - W2 B-fragments moved to LDS (32 KB, packed once per block) to free
//     32 registers, which pay for:
//   - T14 async-STAGE split: next tile's x loads (8x float4/thread) are
//     issued right after the current stage barrier and consumed (convert +
//     ds_write) at the top of the next grid-stride iteration, hiding HBM
//     latency under GEMM1/GEMM2/LN. Halo rows (2) load synchronously.
// Register total stays ~252 <= 256 -> 2 blocks/CU (8 waves/CU), like v1.

typedef __bf16 bf16x8 __attribute__((ext_vector_type(8)));
typedef __bf16 bf16x4 __attribute__((ext_vector_type(4)));
typedef float  f32x4  __attribute__((ext_vector_type(4)));

#define H      128
#define NB     65536        // rows per batch
#define TILE   64
#define XS     136          // x LDS stride (bf16 elems): 68 words ≡ 4 mod 32
#define HSS    136          // h LDS stride (bf16 elems)
#define VS     132          // v LDS stride (f32 elems)
#define NTILES 4096         // 4 * 65536 / 64
#define GRID   512          // 2 blocks/CU * 256 CUs

__global__ __launch_bounds__(256, 2)
void cbb_kernel(const float* __restrict__ x, const float* __restrict__ W1,
                const float* __restrict__ b1, const float* __restrict__ W2,
                const float* __restrict__ b2, const float* __restrict__ gamma,
                const float* __restrict__ beta, float* __restrict__ out) {
    // region A: xs (66*136 bf16) + hs (64*136 bf16) = 35360 B
    // region B (aliased): vs (64*132 f32) = 33792 B
    __shared__ __align__(16) char raw[(66 * XS + 64 * HSS) * 2];
    __bf16* xs = (__bf16*)raw;
    __bf16* hs = xs + 66 * XS;
    float*  vs = (float*)raw;
    __shared__ __align__(16) __bf16 w2s[16384];   // W2 frags, 32 KB, persistent
    __shared__ float s_mu[64], s_rs[64], s_gamma[128], s_beta[128];

    const int tid  = threadIdx.x;
    const int wid  = tid >> 6;
    const int lane = tid & 63;
    const int l    = lane & 15;   // MFMA m / n index
    const int g    = lane >> 4;   // MFMA quad (k-chunk select)
    const int col0 = wid * 32;
    const int c0   = col0 + l;
    const int c1   = col0 + 16 + l;

    if (tid < 128) { s_gamma[tid] = gamma[tid]; s_beta[tid] = beta[tid]; }

    const float b1r0 = b1[c0], b1r1 = b1[c1];
    const float b2r0 = b2[c0], b2r1 = b2[c1];

    // ---- W1 B-fragments persistent in registers (this wave's 32-col slice) ----
    bf16x8 w1f[12][2];
#pragma unroll
    for (int ks = 0; ks < 12; ++ks) {
#pragma unroll
        for (int ct = 0; ct < 2; ++ct) {
            const int cc = col0 + ct * 16 + l;
            bf16x8 f;
#pragma unroll
            for (int j = 0; j < 8; ++j)
                f[j] = (__bf16)W1[(ks * 32 + g * 8 + j) * H + cc];
            w1f[ks][ct] = f;
        }
    }

    // ---- W2 B-fragments -> LDS, fragment-ordered (once per block) ----
    // layout: w2s[w*4096 + ks*1024 + ct*512 + lane*8 + j]
    for (int idx = tid; idx < 16384; idx += 256) {
        const int j  = idx & 7;
        const int ln = (idx >> 3) & 63;
        const int ct = (idx >> 9) & 1;
        const int ks = (idx >> 10) & 3;
        const int w  = idx >> 12;
        const int row = ks * 32 + (ln >> 4) * 8 + j;
        const int col = w * 32 + ct * 16 + (ln & 15);
        w2s[idx] = (__bf16)W2[row * H + col];
    }
    const __bf16* w2w = w2s + wid * 4096;

    // ---- T14 prefetch: rows 0..63 of the 66-row halo tile, 8 float4/thread ----
    float4 xreg[8];
    {
        const int t = blockIdx.x;
        const int b  = t >> 10;
        const int n0 = (t & 1023) << 6;
        const size_t rowbase = (size_t)b * NB;
#pragma unroll
        for (int s = 0; s < 8; ++s) {
            const int q = tid + s * 256;            // q < 2048 -> rows 0..63
            const int r = q >> 5, c = q & 31;
            const int grow = (n0 - 1 + r + NB) & (NB - 1);
            xreg[s] = *(const float4*)(x + ((rowbase + grow) * H + c * 4));
        }
    }

    for (int t = blockIdx.x; t < NTILES; t += GRID) {
        const int b  = t >> 10;
        const int n0 = (t & 1023) << 6;
        const size_t rowbase = (size_t)b * NB;

        __syncthreads();  // protect vs (aliases xs) from previous iteration readers

        // ---- stage: consume prefetched regs -> xs (bf16); halo rows sync ----
#pragma unroll
        for (int s = 0; s < 8; ++s) {
            const int q = tid + s * 256;
            const int r = q >> 5, c = q & 31;
            bf16x4 v4;
            v4[0] = (__bf16)xreg[s].x; v4[1] = (__bf16)xreg[s].y;
            v4[2] = (__bf16)xreg[s].z; v4[3] = (__bf16)xreg[s].w;
            *(bf16x4*)(xs + r * XS + c * 4) = v4;
        }
        if (tid < 64) {                              // rows 64,65 (tail of halo)
            const int q = 2048 + tid;
            const int r = q >> 5, c = q & 31;
            const int grow = (n0 - 1 + r + NB) & (NB - 1);
            const float4 f = *(const float4*)(x + ((rowbase + grow) * H + c * 4));
            bf16x4 v4;
            v4[0] = (__bf16)f.x; v4[1] = (__bf16)f.y;
            v4[2] = (__bf16)f.z; v4[3] = (__bf16)f.w;
            *(bf16x4*)(xs + r * XS + c * 4) = v4;
        }
        __syncthreads();

        // ---- issue next tile's loads; they fly under GEMM1/GEMM2/LN ----
        if (t + GRID < NTILES) {
            const int tn  = t + GRID;
            const int bn  = tn >> 10;
            const int n0n = (tn & 1023) << 6;
            const size_t rbn = (size_t)bn * NB;
#pragma unroll
            for (int s = 0; s < 8; ++s) {
                const int q = tid + s * 256;
                const int r = q >> 5, c = q & 31;
                const int grow = (n0n - 1 + r + NB) & (NB - 1);
                xreg[s] = *(const float4*)(x + ((rbn + grow) * H + c * 4));
            }
        }

        // ---- GEMM1: h = relu(cat @ W1 + b1), cat via row offsets 0/1/2 ----
        f32x4 acc[4][2];
#pragma unroll
        for (int rt = 0; rt < 4; ++rt)
#pragma unroll
            for (int ct = 0; ct < 2; ++ct)
                acc[rt][ct] = (f32x4){0.f, 0.f, 0.f, 0.f};

#pragma unroll
        for (int rt = 0; rt < 4; ++rt) {
            const int rb = rt * 16 + l;
#pragma unroll
            for (int ks = 0; ks < 12; ++ks) {
                const int k = ks * 32 + g * 8;          // k in [0,384)
                const bf16x8 a = *(const bf16x8*)(xs + (rb + (k >> 7)) * XS + (k & 127));
                acc[rt][0] = __builtin_amdgcn_mfma_f32_16x16x32_bf16(a, w1f[ks][0], acc[rt][0], 0, 0, 0);
                acc[rt][1] = __builtin_amdgcn_mfma_f32_16x16x32_bf16(a, w1f[ks][1], acc[rt][1], 0, 0, 0);
            }
        }

        // relu + bias -> hs (bf16, row-major), C-layout scatter
#pragma unroll
        for (int rt = 0; rt < 4; ++rt) {
#pragma unroll
            for (int i = 0; i < 4; ++i) {
                const int row = rt * 16 + g * 4 + i;
                hs[row * HSS + c0] = (__bf16)fmaxf(acc[rt][0][i] + b1r0, 0.f);
                hs[row * HSS + c1] = (__bf16)fmaxf(acc[rt][1][i] + b1r1, 0.f);
            }
        }
        __syncthreads();

        // ---- GEMM2: delta = h @ W2 (W2 frags from LDS) ----
        f32x4 acc2[4][2];
#pragma unroll
        for (int rt = 0; rt < 4; ++rt)
#pragma unroll
            for (int ct = 0; ct < 2; ++ct)
                acc2[rt][ct] = (f32x4){0.f, 0.f, 0.f, 0.f};

#pragma unroll
        for (int ks = 0; ks < 4; ++ks) {
            const bf16x8 wf0 = *(const bf16x8*)(w2w + ks * 1024 + lane * 8);
            const bf16x8 wf1 = *(const bf16x8*)(w2w + ks * 1024 + 512 + lane * 8);
#pragma unroll
            for (int rt = 0; rt < 4; ++rt) {
                const bf16x8 a = *(const bf16x8*)(hs + (rt * 16 + l) * HSS + ks * 32 + g * 8);
                acc2[rt][0] = __builtin_amdgcn_mfma_f32_16x16x32_bf16(a, wf0, acc2[rt][0], 0, 0, 0);
                acc2[rt][1] = __builtin_amdgcn_mfma_f32_16x16x32_bf16(a, wf1, acc2[rt][1], 0, 0, 0);
            }
        }

        // ---- residual: v = x + delta + b2 (x from bf16 LDS tile, row+1) ----
#pragma unroll
        for (int rt = 0; rt < 4; ++rt) {
#pragma unroll
            for (int i = 0; i < 4; ++i) {
                const int row = rt * 16 + g * 4 + i;
                acc2[rt][0][i] += b2r0 + (float)xs[(row + 1) * XS + c0];
                acc2[rt][1][i] += b2r1 + (float)xs[(row + 1) * XS + c1];
            }
        }
        __syncthreads();  // all xs/hs reads done; vs may now clobber them

#pragma unroll
        for (int rt = 0; rt < 4; ++rt) {
#pragma unroll
            for (int i = 0; i < 4; ++i) {
                const int row = rt * 16 + g * 4 + i;
                vs[row * VS + c0] = acc2[rt][0][i];
                vs[row * VS + c1] = acc2[rt][1][i];
            }
        }
        __syncthreads();

        // ---- LN stats: 4 threads per row ----
        {
            const int row = tid >> 2;
            const int cb  = (tid & 3) * 32;
            float s = 0.f, qq = 0.f;
#pragma unroll
            for (int c8 = 0; c8 < 8; ++c8) {
                const f32x4 vv = *(const f32x4*)(vs + row * VS + cb + c8 * 4);
#pragma unroll
                for (int e = 0; e < 4; ++e) { s += vv[e]; qq += vv[e] * vv[e]; }
            }
            s  += __shfl_xor(s, 1, 4);  s  += __shfl_xor(s, 2, 4);
            qq += __shfl_xor(qq, 1, 4); qq += __shfl_xor(qq, 2, 4);
            const float muv = s * (1.f / 128.f);
            const float var = qq * (1.f / 128.f) - muv * muv;
            if ((tid & 3) == 0) { s_mu[row] = muv; s_rs[row] = rsqrtf(var + 1e-5f); }
        }
        __syncthreads();

        // ---- normalize + relu + coalesced float4 store ----
        {
            const int row = tid >> 2;
            const int cb  = (tid & 3) * 32;
            const float muv = s_mu[row], rv = s_rs[row];
            float* op = out + (rowbase + n0 + row) * H + cb;
#pragma unroll
            for (int c8 = 0; c8 < 8; ++c8) {
                const f32x4 vv = *(const f32x4*)(vs + row * VS + cb + c8 * 4);
                const f32x4 gm = *(const f32x4*)(s_gamma + cb + c8 * 4);
                const f32x4 bt = *(const f32x4*)(s_beta + cb + c8 * 4);
                f32x4 o;
#pragma unroll
                for (int e = 0; e < 4; ++e)
                    o[e] = fmaxf((vv[e] - muv) * rv * gm[e] + bt[e], 0.f);
                *(f32x4*)(op + c8 * 4) = o;
            }
        }
    }
}

extern "C" void kernel_launch(void* const* d_in, const int* in_sizes, int n_in,
                              void* d_out, int out_size, void* d_ws, size_t ws_size,
                              hipStream_t stream) {
    const float* x     = (const float*)d_in[0];
    const float* W1    = (const float*)d_in[1];
    const float* b1    = (const float*)d_in[2];
    const float* W2    = (const float*)d_in[3];
    const float* b2    = (const float*)d_in[4];
    const float* gamma = (const float*)d_in[5];
    const float* beta  = (const float*)d_in[6];
    float* out = (float*)d_out;

    // 512 blocks = 2 resident blocks/CU * 256 CUs; grid-stride over 4096 tiles
    cbb_kernel<<<GRID, 256, 0, stream>>>(x, W1, b1, W2, b2, gamma, beta, out);
}